// Round 1
// baseline (112.930 us; speedup 1.0000x reference)
//
#include <hip/hip_runtime.h>

// NT-Xent positive-pair loss:
//   cos_k = dot(z_i[k], z_j[k]) / max(||z_i[k]|| * ||z_j[k]||, EPS)
//   loss  = sum_k (cos_k / T)^2 * 2 / N^2,  N = 2B
// B = 16384, D = 512, T = 0.5, EPS = 1e-8.

constexpr int   B_ROWS = 16384;
constexpr int   D_DIM  = 512;
constexpr float EPS    = 1e-8f;
// pos = cos / 0.5 = cos * 2; final scale = 2 / N^2 with N = 32768.
constexpr float INV_TEMP = 2.0f;
constexpr float SCALE    = 2.0f / (32768.0f * 32768.0f);  // 1.8626451e-9f

__global__ __launch_bounds__(256) void ntxent_pos_loss_kernel(
    const float* __restrict__ zi,
    const float* __restrict__ zj,
    float* __restrict__ out)
{
    const int lane        = threadIdx.x & 63;
    const int wave_in_blk = threadIdx.x >> 6;
    const int wave        = blockIdx.x * 4 + wave_in_blk;
    const int nwaves      = gridDim.x * 4;

    float acc = 0.0f;  // only meaningful on lane 0

    for (int row = wave; row < B_ROWS; row += nwaves) {
        const float4* a4 = (const float4*)(zi + (size_t)row * D_DIM);
        const float4* b4 = (const float4*)(zj + (size_t)row * D_DIM);

        // Lane l reads f4[l] and f4[l+64]: each instruction covers a
        // contiguous, aligned 1 KiB span per wave (64 lanes x 16 B).
        float4 a0 = a4[lane];
        float4 a1 = a4[lane + 64];
        float4 b0 = b4[lane];
        float4 b1 = b4[lane + 64];

        float dot = a0.x * b0.x + a0.y * b0.y + a0.z * b0.z + a0.w * b0.w
                  + a1.x * b1.x + a1.y * b1.y + a1.z * b1.z + a1.w * b1.w;
        float na  = a0.x * a0.x + a0.y * a0.y + a0.z * a0.z + a0.w * a0.w
                  + a1.x * a1.x + a1.y * a1.y + a1.z * a1.z + a1.w * a1.w;
        float nb  = b0.x * b0.x + b0.y * b0.y + b0.z * b0.z + b0.w * b0.w
                  + b1.x * b1.x + b1.y * b1.y + b1.z * b1.z + b1.w * b1.w;

        // 64-lane butterfly reduction (wave = 64 on gfx950).
        #pragma unroll
        for (int off = 32; off > 0; off >>= 1) {
            dot += __shfl_down(dot, off, 64);
            na  += __shfl_down(na,  off, 64);
            nb  += __shfl_down(nb,  off, 64);
        }

        if (lane == 0) {
            float norm_prod = sqrtf(na) * sqrtf(nb);
            float cosv = dot / fmaxf(norm_prod, EPS);
            float pos  = cosv * INV_TEMP;
            acc += pos * pos;
        }
    }

    __shared__ float s[4];
    if (lane == 0) s[wave_in_blk] = acc;
    __syncthreads();
    if (threadIdx.x == 0) {
        float t = (s[0] + s[1]) + (s[2] + s[3]);
        atomicAdd(out, t * SCALE);
    }
}

extern "C" void kernel_launch(void* const* d_in, const int* in_sizes, int n_in,
                              void* d_out, int out_size, void* d_ws, size_t ws_size,
                              hipStream_t stream)
{
    const float* zi = (const float*)d_in[0];
    const float* zj = (const float*)d_in[1];
    float* out = (float*)d_out;

    // Harness re-poisons d_out with 0xAA before every timed launch.
    hipMemsetAsync(out, 0, sizeof(float), stream);

    // 2048 blocks x 4 waves = 8192 waves -> 2 rows per wave.
    ntxent_pos_loss_kernel<<<2048, 256, 0, stream>>>(zi, zj, out);
}

// Round 2
// 92.323 us; speedup vs baseline: 1.2232x; 1.2232x over previous
//
#include <hip/hip_runtime.h>

// NT-Xent positive-pair loss:
//   cos_k = dot(z_i[k], z_j[k]) / max(||z_i[k]|| * ||z_j[k]||, EPS)
//   loss  = sum_k (cos_k / T)^2 * 2 / N^2,  N = 2B
// B = 16384, D = 512, T = 0.5, EPS = 1e-8.
//
// Structure: kernel 1 = 1024 blocks x 256 thr, 16 lanes per row (4 rows/wave,
// 16 rows/block-wavegroup... 4 waves * 4 rows = 16 rows/block), writes one
// partial per block to d_ws (plain store -> no d_out/ws init needed).
// Kernel 2 = single block, reduces 1024 partials, writes the scalar.

constexpr int   D_DIM  = 512;
constexpr float EPS    = 1e-8f;
constexpr float INV_TEMP = 2.0f;                          // 1 / 0.5
constexpr float SCALE    = 2.0f / (32768.0f * 32768.0f);  // 2 / N^2

__global__ __launch_bounds__(256) void ntxent_partial_kernel(
    const float* __restrict__ zi,
    const float* __restrict__ zj,
    float* __restrict__ partials)
{
    const int lane        = threadIdx.x & 63;
    const int wave_in_blk = threadIdx.x >> 6;
    const int g    = lane & 15;   // lane within 16-lane row-group
    const int grp  = lane >> 4;   // 0..3: which row this group handles
    const int wave = blockIdx.x * 4 + wave_in_blk;   // 0..4095
    const int row  = wave * 4 + grp;                 // 0..16383, one pass

    const float4* a4 = (const float4*)(zi + (size_t)row * D_DIM);
    const float4* b4 = (const float4*)(zj + (size_t)row * D_DIM);

    float dot = 0.0f, na = 0.0f, nb = 0.0f;
    // 512 floats / 16 lanes = 8 float4 per lane; each load instruction covers
    // 4 contiguous 256B chunks in 4 adjacent rows (full cache lines).
    #pragma unroll
    for (int k = 0; k < 8; ++k) {
        float4 a = a4[g + 16 * k];
        float4 b = b4[g + 16 * k];
        dot += a.x * b.x + a.y * b.y + a.z * b.z + a.w * b.w;
        na  += a.x * a.x + a.y * a.y + a.z * a.z + a.w * a.w;
        nb  += b.x * b.x + b.y * b.y + b.z * b.z + b.w * b.w;
    }

    // Reduce across the 16 lanes of the row-group (4 xor steps).
    #pragma unroll
    for (int m = 8; m >= 1; m >>= 1) {
        dot += __shfl_xor(dot, m, 64);
        na  += __shfl_xor(na,  m, 64);
        nb  += __shfl_xor(nb,  m, 64);
    }

    float acc = 0.0f;
    if (g == 0) {   // 4 group-leader lanes per wave, one row each
        float norm_prod = sqrtf(na) * sqrtf(nb);
        float cosv = dot / fmaxf(norm_prod, EPS);
        float pos  = cosv * INV_TEMP;
        acc = pos * pos;
    }
    // Sum the 4 group results across the wave (lanes 0,16,32,48 hold values).
    acc += __shfl_xor(acc, 16, 64);
    acc += __shfl_xor(acc, 32, 64);

    __shared__ float s[4];
    if (lane == 0) s[wave_in_blk] = acc;
    __syncthreads();
    if (threadIdx.x == 0)
        partials[blockIdx.x] = (s[0] + s[1]) + (s[2] + s[3]);
}

__global__ __launch_bounds__(256) void ntxent_finalize_kernel(
    const float* __restrict__ partials,
    float* __restrict__ out)
{
    // 1024 partials, 256 threads -> 4 each.
    float v = partials[threadIdx.x]
            + partials[threadIdx.x + 256]
            + partials[threadIdx.x + 512]
            + partials[threadIdx.x + 768];
    #pragma unroll
    for (int m = 32; m >= 1; m >>= 1)
        v += __shfl_xor(v, m, 64);

    __shared__ float s[4];
    if ((threadIdx.x & 63) == 0) s[threadIdx.x >> 6] = v;
    __syncthreads();
    if (threadIdx.x == 0)
        out[0] = ((s[0] + s[1]) + (s[2] + s[3])) * SCALE;
}

extern "C" void kernel_launch(void* const* d_in, const int* in_sizes, int n_in,
                              void* d_out, int out_size, void* d_ws, size_t ws_size,
                              hipStream_t stream)
{
    const float* zi = (const float*)d_in[0];
    const float* zj = (const float*)d_in[1];
    float* partials = (float*)d_ws;   // 1024 floats = 4 KiB of scratch
    float* out = (float*)d_out;

    ntxent_partial_kernel<<<1024, 256, 0, stream>>>(zi, zj, partials);
    ntxent_finalize_kernel<<<1, 256, 0, stream>>>(partials, out);
}